// Round 7
// baseline (707.118 us; speedup 1.0000x reference)
//
#include <hip/hip_runtime.h>
#include <math.h>

#define NROWS 65536
#define KCOLS 1024
#define GBLK  256
#define STOP_TOL 24.0f  // absmax is fp8-grid dominated (2^-9, stable tol 0.1->8);
                        // tol 24 adds <=~5e-4 worst case; threshold 7.1e-3
#define MAXIT 2000

typedef float f32x2 __attribute__((ext_vector_type(2)));
typedef float f32x4v __attribute__((ext_vector_type(4)));

__device__ __forceinline__ float wredf(float v){
#pragma unroll
  for (int m = 1; m < 64; m <<= 1) v += __shfl_xor(v, m);
  return v;
}
__device__ __forceinline__ float wmaxf(float v){
#pragma unroll
  for (int m = 1; m < 64; m <<= 1) v = fmaxf(v, __shfl_xor(v, m));
  return v;
}

// Single fused persistent kernel. Per-iter row pass restructured:
//   dot pass (all 16 rows) -> one 17-shfl reduce-scatter (lane m owns row
//   rev4(m)) -> readlane beta broadcast -> scatter pass.
__global__ __launch_bounds__(1024, 4) void sink_kernel(
    const float* __restrict__ logits, const float* __restrict__ kdist,
    float* __restrict__ out,
    double* colsum, float* sacc4, float* errP, unsigned* cntS, unsigned* cnt0,
    char* instW)
{
  constexpr int REV4[16] = {0,8,4,12,2,10,6,14,1,9,5,13,3,11,7,15};

  __shared__ __align__(16) char sraw[65536]; // comb_d(64K) / sort(28K) / comb(64K)
  float*  comb   = (float*)sraw;
  double* comb_d = (double*)sraw;            // 8 x 1024 f64
  double* skey   = (double*)sraw;            // 8 KB
  int*    ssidx  = (int*)(sraw + 8192);      // 4 KB
  double* skperm = (double*)(sraw + 12288);  // 8 KB
  double* sred   = (double*)(sraw + 20480);  // 8 KB
  __shared__ float lalpha[1024];
  __shared__ float lerr[16];
  __shared__ float lerr8[8];

  const int tid = threadIdx.x, lane = tid & 63, w = tid >> 6;   // 16 waves
  const int bid = blockIdx.x;
  const size_t row0 = ((size_t)bid * 16 + w) * 16;
  const float cNf = 1.0f / (float)NROWS;

  unsigned ps[16][4];                 // 16 rows x 16 fp8 cols per lane
  float bprev = 1.0f;                 // valid on lanes < 16 (owner of row REV4[lane])
  float cacc[16];
#pragma unroll
  for (int e = 0; e < 16; ++e) cacc[e] = 0.f;

  // ---- build: f32 softmax -> fp8 (per-row scale 256, Sinkhorn-invariant) + colsum partials ----
#pragma unroll
  for (int rr = 0; rr < 16; ++rr) {
    const float4* rp = (const float4*)(logits + (row0 + rr) * KCOLS);
    float4 v0 = rp[4*lane+0], v1 = rp[4*lane+1], v2 = rp[4*lane+2], v3 = rp[4*lane+3];
    float xs[16] = {v0.x,v0.y,v0.z,v0.w, v1.x,v1.y,v1.z,v1.w,
                    v2.x,v2.y,v2.z,v2.w, v3.x,v3.y,v3.z,v3.w};
    float mx = xs[0];
#pragma unroll
    for (int e = 1; e < 16; ++e) mx = fmaxf(mx, xs[e]);
    mx = wmaxf(mx);
    float ev[16]; float ls = 0.f;
#pragma unroll
    for (int e = 0; e < 16; ++e) { ev[e] = __expf(xs[e] - mx); ls += ev[e]; }
    ls = wredf(ls);
    if (lane == REV4[rr]) bprev = cNf / (256.0f * ls);  // owner lane of row rr
    const float inv = 1.0f / ls;
#pragma unroll
    for (int e = 0; e < 16; ++e) cacc[e] += ev[e] * inv;
#pragma unroll
    for (int q = 0; q < 4; ++q) {
      int u = 0;
      u = __builtin_amdgcn_cvt_pk_fp8_f32(ev[4*q+0]*256.0f, ev[4*q+1]*256.0f, u, false);
      u = __builtin_amdgcn_cvt_pk_fp8_f32(ev[4*q+2]*256.0f, ev[4*q+3]*256.0f, u, true);
      ps[rr][q] = (unsigned)u;
    }
  }

  // ---- one-time f64 colsum: 16-wave LDS combine -> 1024 f64 atomics per block ----
  if (w < 8) {
#pragma unroll
    for (int e = 0; e < 16; ++e) comb_d[w*1024 + e*64 + lane] = (double)cacc[e];
  }
  __syncthreads();
  if (w >= 8) {
#pragma unroll
    for (int e = 0; e < 16; ++e) comb_d[(w-8)*1024 + e*64 + lane] += (double)cacc[e];
  }
  __syncthreads();
  {
    double part = 0.0;
#pragma unroll
    for (int j = 0; j < 8; ++j) part += comb_d[j*1024 + tid];
    const int c = 16*(tid & 63) + (tid >> 6);
    __hip_atomic_fetch_add(&colsum[c], part, __ATOMIC_RELAXED, __HIP_MEMORY_SCOPE_AGENT);
  }
  __syncthreads();

  // ---- device barrier #0 (colsum complete) ----
  if (tid == 0) {
    __threadfence();
    __hip_atomic_fetch_add(cnt0, 1u, __ATOMIC_RELEASE, __HIP_MEMORY_SCOPE_AGENT);
    while (__hip_atomic_load(cnt0, __ATOMIC_RELAXED, __HIP_MEMORY_SCOPE_AGENT) < (unsigned)GBLK)
      __builtin_amdgcn_s_sleep(1);
    __builtin_amdgcn_fence(__ATOMIC_ACQUIRE, "agent");
  }
  __syncthreads();

  // ---- redundant per-block bitonic argsort + r + alpha_1 ----
  float rF;
  {
    const int t = tid;
    const double cs = __hip_atomic_load(&colsum[t], __ATOMIC_RELAXED, __HIP_MEMORY_SCOPE_AGENT);
    skey[t] = cs; ssidx[t] = t;
    __syncthreads();
    for (int k = 2; k <= 1024; k <<= 1) {
      for (int j = k >> 1; j > 0; j >>= 1) {
        const int pp = t ^ j;
        if (pp > t) {
          const bool up = ((t & k) == 0);
          double a = skey[t], b = skey[pp];
          if ((a > b) == up) {
            skey[t] = b; skey[pp] = a;
            int tm = ssidx[t]; ssidx[t] = ssidx[pp]; ssidx[pp] = tm;
          }
        }
        __syncthreads();
      }
    }
    skperm[ssidx[t]] = (double)kdist[t];
    __syncthreads();
    const double rr_d = 1.0 / skperm[t];
    sred[t] = rr_d;
    __syncthreads();
    for (int s2 = 512; s2 > 0; s2 >>= 1) { if (t < s2) sred[t] += sred[t+s2]; __syncthreads(); }
    const double r = rr_d / sred[0];
    rF = (float)r;                                    // thread t owns column t
    const float a1 = (float)(r / (cs / (double)NROWS));
    lalpha[(t & 15)*64 + (t >> 4)] = a1;              // transposed store
    __syncthreads();
  }

  f32x2 alo2[8], sacc2[8];
  int iter = 0;

  for (;;) {
    // load alpha fragments (conflict-free transposed reads); alo2 = alpha^{(iter)}
#pragma unroll
    for (int q = 0; q < 8; ++q) {
      alo2[q].x = lalpha[(2*q  )*64 + lane];
      alo2[q].y = lalpha[(2*q+1)*64 + lane];
    }

    // stop check (lag-1: err from previous iteration; break keeps the NEWEST alpha)
    if (iter >= MAXIT) break;
    if (iter > 0) {
      float ep = 0.f;
#pragma unroll
      for (int j = 0; j < 8; ++j) ep += lerr8[j];
      if (ep <= STOP_TOL) break;
    }

    // instrumentation: all blocks nt-store 2KB/iter (512KB/iter device-wide),
    // issued at loop-top so it drains under the row pass. I = dWRITE/(512+~550)KiB.
    if (instW != nullptr && tid < 128) {
      f32x4v vv = {(float)iter, (float)bid, 2.f, 3.f};
      __builtin_nontemporal_store(vv,
        (f32x4v*)(instW + ((size_t)(iter & 3) << 19) + ((size_t)bid << 11) + ((size_t)tid << 4)));
    }

    const int p = iter & 3;
    const unsigned genu = (unsigned)(iter >> 2) + 1u;

    // lag-2 zeroing of rotating buffers (ordered by the arrival/acquire chain)
    {
      const int pz = (iter + 2) & 3;
      if (tid < 32)
        __hip_atomic_store(&sacc4[pz*8192 + bid*32 + tid], 0.f,
                           __ATOMIC_RELAXED, __HIP_MEMORY_SCOPE_AGENT);
      if (bid == 0 && tid < 8)
        __hip_atomic_store(&errP[(pz*8 + tid)*16], 0.f,
                           __ATOMIC_RELAXED, __HIP_MEMORY_SCOPE_AGENT);
    }

    float errloc = 0.f;

    // ---- dot pass: t16[rr] = this lane's 16-col partial of row rr's dot ----
    float t16[16];
#pragma unroll
    for (int rr = 0; rr < 16; ++rr) {
      f32x2 t2 = {0.f, 0.f};
#pragma unroll
      for (int q = 0; q < 4; ++q) {
        f32x2 lo = __builtin_amdgcn_cvt_pk_f32_fp8((int)ps[rr][q], false);
        f32x2 hi = __builtin_amdgcn_cvt_pk_f32_fp8((int)ps[rr][q], true);
        t2 = t2 + lo * alo2[2*q] + hi * alo2[2*q+1];
      }
      t16[rr] = t2.x + t2.y;
    }

    // ---- reduce-scatter butterfly: 17 shfl total; lane m ends with full
    //      tsum of row REV4[m] (replicated across the 4 16-lane groups) ----
    float k8[8];
#pragma unroll
    for (int j = 0; j < 8; ++j) {
      const float send = (lane & 1) ? t16[j] : t16[j+8];
      const float recv = __shfl_xor(send, 1);
      k8[j] = ((lane & 1) ? t16[j+8] : t16[j]) + recv;
    }
    float k4[4];
#pragma unroll
    for (int j = 0; j < 4; ++j) {
      const float send = (lane & 2) ? k8[j] : k8[j+4];
      const float recv = __shfl_xor(send, 2);
      k4[j] = ((lane & 2) ? k8[j+4] : k8[j]) + recv;
    }
    float k2[2];
#pragma unroll
    for (int j = 0; j < 2; ++j) {
      const float send = (lane & 4) ? k4[j] : k4[j+2];
      const float recv = __shfl_xor(send, 4);
      k2[j] = ((lane & 4) ? k4[j+2] : k4[j]) + recv;
    }
    float k1;
    {
      const float send = (lane & 8) ? k2[0] : k2[1];
      const float recv = __shfl_xor(send, 8);
      k1 = ((lane & 8) ? k2[1] : k2[0]) + recv;
    }
    k1 += __shfl_xor(k1, 16);
    k1 += __shfl_xor(k1, 32);

    const float bnew = cNf * __builtin_amdgcn_rcpf(k1);
    if (lane < 16) {                       // owner of row REV4[lane]
      errloc += fabsf(bprev * k1 * (float)NROWS - 1.0f);   // |bprev/bnew - 1|
      bprev = bnew;
    }
    // broadcast beta in row order via readlane (uniform -> SGPR)
    float barr[16];
#pragma unroll
    for (int r = 0; r < 16; ++r)
      barr[r] = __int_as_float(
        __builtin_amdgcn_readlane(__float_as_int(bnew), REV4[r]));

    // ---- scatter pass: sacc += beta_r * PS[r][:] ----
#pragma unroll
    for (int q = 0; q < 8; ++q) sacc2[q] = (f32x2){0.f, 0.f};
#pragma unroll
    for (int rr = 0; rr < 16; ++rr) {
      const f32x2 b2 = {barr[rr], barr[rr]};
#pragma unroll
      for (int q = 0; q < 4; ++q) {
        f32x2 lo = __builtin_amdgcn_cvt_pk_f32_fp8((int)ps[rr][q], false);
        f32x2 hi = __builtin_amdgcn_cvt_pk_f32_fp8((int)ps[rr][q], true);
        sacc2[2*q  ] = sacc2[2*q  ] + lo * b2;
        sacc2[2*q+1] = sacc2[2*q+1] + hi * b2;
      }
    }

    // 16-wave LDS combine + partition-major (8) packed global atomics
#pragma unroll
    for (int e = 0; e < 16; ++e)
      comb[w*1024 + e*64 + lane] = sacc2[e >> 1][e & 1];
    errloc = wredf(errloc);
    if (lane == 0) lerr[w] = errloc;
    __syncthreads();
    {
      float tot = 0.f;
#pragma unroll
      for (int ww = 0; ww < 16; ++ww) tot += comb[ww*1024 + tid];
      const int col = 16*(tid & 63) + (tid >> 6);
      __hip_atomic_fetch_add(&sacc4[p*8192 + (bid & 7)*1024 + col], tot,
                             __ATOMIC_RELAXED, __HIP_MEMORY_SCOPE_AGENT);
    }
    if (tid == 0) {
      float es = 0.f;
#pragma unroll
      for (int i = 0; i < 16; ++i) es += lerr[i];
      __hip_atomic_fetch_add(&errP[(p*8 + (bid & 7))*16], es,
                             __ATOMIC_RELAXED, __HIP_MEMORY_SCOPE_AGENT);
    }
    __syncthreads();   // drains this block's atomics before the arrival release

    // flat barrier: release-add own sub-counter; poll all 8 (relaxed) + one acquire fence
    if (tid == 0) {
      __threadfence();
      __hip_atomic_fetch_add(&cntS[(p*8 + (bid & 7))*16], 1u,
                             __ATOMIC_RELEASE, __HIP_MEMORY_SCOPE_AGENT);
      const unsigned tgt = 32u * genu;
      for (;;) {
        unsigned mn = 0xffffffffu;
#pragma unroll
        for (int j = 0; j < 8; ++j) {
          unsigned cj = __hip_atomic_load(&cntS[(p*8 + j)*16],
                                          __ATOMIC_RELAXED, __HIP_MEMORY_SCOPE_AGENT);
          mn = (cj < mn) ? cj : mn;
        }
        if (mn >= tgt) break;
        __builtin_amdgcn_s_sleep(1);
      }
      __builtin_amdgcn_fence(__ATOMIC_ACQUIRE, "agent");
    }
    __syncthreads();

    // every block computes alpha^{(iter+1)} locally (plain coalesced loads:
    // safe after the agent-acquire fence this block just executed)
    {
      float s = 0.f;
      const float* sp = &sacc4[p*8192 + tid];
#pragma unroll
      for (int part = 0; part < 8; ++part) s += sp[part*1024];
      lalpha[(tid & 15)*64 + (tid >> 4)] = rF / s;
    }
    if (tid < 512 && (tid & 63) == 0) {
      const int j = tid >> 6;                 // lane0 of waves 0..7: one err part each
      lerr8[j] = errP[(p*8 + j)*16];
    }
    __syncthreads();
    ++iter;
  }

  // ---- final: out[n,k] = exp(l-m)*alpha_k / rowsum, f32 from logits ----
  float af[16];
#pragma unroll
  for (int e = 0; e < 16; ++e) af[e] = alo2[e >> 1][e & 1];
  for (int rr = 0; rr < 16; ++rr) {
    const size_t n = row0 + rr;
    const float4* rp = (const float4*)(logits + n * KCOLS);
    float4 v0 = rp[4*lane+0], v1 = rp[4*lane+1], v2 = rp[4*lane+2], v3 = rp[4*lane+3];
    float xs[16] = {v0.x,v0.y,v0.z,v0.w, v1.x,v1.y,v1.z,v1.w,
                    v2.x,v2.y,v2.z,v2.w, v3.x,v3.y,v3.z,v3.w};
    float mx = xs[0];
#pragma unroll
    for (int e = 1; e < 16; ++e) mx = fmaxf(mx, xs[e]);
    mx = wmaxf(mx);
    float wv[16]; float ts = 0.f;
#pragma unroll
    for (int e = 0; e < 16; ++e) { wv[e] = __expf(xs[e] - mx) * af[e]; ts += wv[e]; }
    ts = wredf(ts);
    const float inv = 1.0f / ts;
    float4* op = (float4*)(out + n * KCOLS);
    op[4*lane+0] = make_float4(wv[0]*inv,  wv[1]*inv,  wv[2]*inv,  wv[3]*inv);
    op[4*lane+1] = make_float4(wv[4]*inv,  wv[5]*inv,  wv[6]*inv,  wv[7]*inv);
    op[4*lane+2] = make_float4(wv[8]*inv,  wv[9]*inv,  wv[10]*inv, wv[11]*inv);
    op[4*lane+3] = make_float4(wv[12]*inv, wv[13]*inv, wv[14]*inv, wv[15]*inv);
  }
}

extern "C" void kernel_launch(void* const* d_in, const int* in_sizes, int n_in,
                              void* d_out, int out_size, void* d_ws, size_t ws_size,
                              hipStream_t stream)
{
  const float* logits = (const float*)d_in[0];
  const float* kdist  = (const float*)d_in[1];
  float* out = (float*)d_out;

  char* ws = (char*)d_ws;
  double*   colsum = (double*)(ws + 0);          // 8 KB
  float*    sacc4  = (float*) (ws + 8192);       // 4 x 8192 f32 = 128 KB (partition-major x8)
  float*    errP   = (float*) (ws + 139264);     // 4 x 8 slots, 64 B apart = 2 KB
  unsigned* cntS   = (unsigned*)(ws + 141312);   // 4 x 8 counters, 64 B apart = 2 KB
  unsigned* cnt0   = (unsigned*)(ws + 143360);
  // instrumentation region: 4 slots x 512 KB at ws+256KB (small gate: 2.5 MB)
  char* instW = (ws_size >= (size_t)(2560 * 1024)) ? (ws + 262144) : nullptr;

  hipMemsetAsync(d_ws, 0, 144 * 1024, stream);
  // 256 blocks x 1024 threads, VGPR<=128 via launch_bounds, ~70KB LDS:
  // one block per CU, all co-resident; in-kernel device barriers.
  hipLaunchKernelGGL(sink_kernel, dim3(GBLK), dim3(1024), 0, stream,
                     logits, kdist, out, colsum, sacc4, errP, cntS, cnt0, instW);
}